// Round 5
// baseline (9420.851 us; speedup 1.0000x reference)
//
#include <hip/hip_runtime.h>
#include <hip/hip_bf16.h>
#include <stdint.h>

#define B_ 64
#define T_ 64
#define G_ 11
#define F_ 4
#define E_ 128
#define H_ 256
#define NG 1024
#define GT_ 704
#define LSEQ 11534336   // G*T*B*H elems per encoder layer

// weight blob region offsets (elements); L-copy of each buffer at +D* offset
#define OFF_WCAT0   0
#define OFF_WCAT123 393216
#define OFF_GCW0    1966080
#define OFF_GCW123  2490368
#define OFF_DWE     3276800
#define OFF_DWS     3407872
#define WBLOB_N     4194304
#define DW  ((size_t)WBLOB_N)     // weight blob lo-offset
#define DH4 ((size_t)46137344)    // hseq lo-offset (4*LSEQ)
#define DE  ((size_t)5767168)     // emb lo-offset
#define DAT ((size_t)16384)       // attn lo-offset
#define DH2 ((size_t)98304)       // h2buf lo-offset (2*192*256)

typedef __attribute__((ext_vector_type(8))) short bf16x8;
typedef __attribute__((ext_vector_type(4))) float f32x4;

__device__ __forceinline__ f32x4 mfma16(bf16x8 a, bf16x8 b, f32x4 c){
  return __builtin_amdgcn_mfma_f32_16x16x32_bf16(a, b, c, 0, 0, 0);
}
__device__ __forceinline__ float sigm(float x){ return 1.f/(1.f+__expf(-x)); }
__device__ __forceinline__ float tanh_(float x){ float e=__expf(2.f*x); return 1.f - 2.f/(e+1.f); }
__device__ __forceinline__ float b2f(__hip_bfloat16 v){ return __bfloat162float(v); }
__device__ __forceinline__ float s2f(short u){
  union { unsigned int u32; float f; } cv;
  cv.u32 = ((unsigned int)(unsigned short)u) << 16;
  return cv.f;
}
__device__ __forceinline__ void splitw(float v, __hip_bfloat16* ph, __hip_bfloat16* pl){
  __hip_bfloat16 h = __float2bfloat16(v);
  *ph = h; *pl = __float2bfloat16(v - __bfloat162float(h));
}
__device__ __forceinline__ unsigned int ld_acq(const unsigned int* p){
  return __hip_atomic_load(p, __ATOMIC_ACQUIRE, __HIP_MEMORY_SCOPE_AGENT);
}
__device__ __forceinline__ void st_rel(unsigned int* p, unsigned int v){
  __hip_atomic_store(p, v, __ATOMIC_RELEASE, __HIP_MEMORY_SCOPE_AGENT);
}

// ---------------- weight conversion fp32 -> split bf16 (hi/lo blobs) -----------
__global__ void k_conv(const float* Wih0, const float* Wihs, const float* Whh,
                       const float* dWih0, const float* dWihs, const float* dWhh,
                       __hip_bfloat16* out)
{
  for (int i = blockIdx.x*blockDim.x + threadIdx.x; i < WBLOB_N; i += gridDim.x*blockDim.x){
    int j = i; float v;
    if (j < 393216) {                       // Wcat0 [1024][384] = [enc_Wih0 | enc_Whh0]
      int n = j/384, k = j%384;
      v = (k<128) ? Wih0[n*128+k] : Whh[n*256 + (k-128)];
    } else if ((j -= 393216) < 1572864) {   // Wcat123 3x[1024][512]
      int l = j/524288; int r = j%524288; int n = r/512, k = r%512;
      v = (k<256) ? Wihs[(l*1024+n)*256+k] : Whh[((l+1)*1024+n)*256 + (k-256)];
    } else if ((j -= 1572864) < 524288) {   // GcW0 [1024][512]
      int n = j/512, k = j%512;
      v = (k<256) ? dWih0[n*384+k] : dWhh[n*256 + (k-256)];
    } else if ((j -= 524288) < 786432) {    // GcW123 3x[1024][256]
      int l = j/262144; int r = j%262144; int n = r/256, k = r%256;
      v = dWhh[((l+1)*1024+n)*256+k];
    } else if ((j -= 786432) < 131072) {    // dWe [1024][128]
      int n = j/128, k = j%128;
      v = dWih0[n*384 + 256 + k];
    } else { j -= 131072; v = dWihs[j]; }   // dWs 3x[1024][256]
    splitw(v, out + i, out + i + DW);
  }
}

// ---------------- emb = relu(xg @ enc_lin_W^T + b), split bf16 ------------------
__global__ void k_emb(const float* x, const float* W, const float* bb, __hip_bfloat16* emb)
{
  const int N = G_*T_*B_*E_;
  for (int i = blockIdx.x*blockDim.x + threadIdx.x; i < N; i += gridDim.x*blockDim.x){
    int e = i & 127; int row = i >> 7;
    int b = row & 63; int t = (row >> 6) & 63; int g = row >> 12;
    const float* xp = x + ((size_t)(b*T_ + t)*G_ + g)*F_;
    float s = bb[e];
#pragma unroll
    for (int f = 0; f < 4; ++f) s += xp[f]*W[e*4+f];
    splitw(fmaxf(s, 0.f), emb + i, emb + i + DE);
  }
}

// ---------------- persistent encoder: block=(l,g,hc), loops t=0..63 -------------
// dataflow flags fe[(l*11+g)*4+hc] = completed steps; wait own-group>=t, producer>=t+1
__global__ __launch_bounds__(256) void k_enc_p(
  __hip_bfloat16* hseq, const __hip_bfloat16* emb, float* cbuf,
  const __hip_bfloat16* wb, const float* bih, const float* bhh, unsigned int* fe)
{
  const int bid = blockIdx.x;
  const int l = bid / 44; const int rem = bid % 44;
  const int g = rem >> 2; const int hc = rem & 3;
  const int grp = l*G_ + g, pgrp = (l-1)*G_ + g;

  const int tid = threadIdx.x;
  const int wv = tid >> 6, lane = tid & 63;
  const int rowblk = (wv & 1) * 32;
  const int colblk = (wv >> 1) * 128;
  const int lm = lane & 15, lk = (lane >> 4) * 8;

  int xstride, K1, wstride; size_t DA;
  const __hip_bfloat16* W;
  const __hip_bfloat16* xbase;   // per-t advance
  if (l == 0){ xbase = emb; xstride = E_; K1 = E_; DA = DE; W = wb + OFF_WCAT0; wstride = 384; }
  else { xbase = hseq + (size_t)(l-1)*LSEQ; xstride = H_; K1 = H_; DA = DH4;
         W = wb + OFF_WCAT123 + (size_t)(l-1)*1024*512; wstride = 512; }

  const __hip_bfloat16* wp[8];
#pragma unroll
  for (int cb = 0; cb < 8; ++cb){
    int v0 = colblk + cb*16 + lm;
    int n = (v0 >> 6)*256 + hc*64 + (v0 & 63);
    wp[cb] = W + (size_t)n*wstride + lk;
  }
  float* cbp = cbuf + ((size_t)l*G_ + g)*B_*H_;
  const float* bi = bih + l*NG; const float* bh = bhh + l*NG;

  __shared__ float glds[64][256];

  for (int t = 0; t < T_; ++t){
    // dataflow waits
    if (t > 0 && tid < 4){
      while (ld_acq(&fe[grp*4 + tid]) < (unsigned int)t) __builtin_amdgcn_s_sleep(1);
    }
    if (l > 0 && tid >= 4 && tid < 8){
      while (ld_acq(&fe[pgrp*4 + (tid-4)]) < (unsigned int)(t+1)) __builtin_amdgcn_s_sleep(1);
    }
    __syncthreads();

    const __hip_bfloat16* xin = xbase + ((size_t)g*T_ + t)*B_*xstride;
    const __hip_bfloat16* hprev = hseq + (size_t)l*LSEQ + ((size_t)g*T_ + (size_t)(t-1))*B_*H_;
    const __hip_bfloat16* ap0 = xin + (size_t)(rowblk + lm)*xstride + lk;
    const __hip_bfloat16* ap1 = xin + (size_t)(rowblk + 16 + lm)*xstride + lk;
    const __hip_bfloat16* hp0 = hprev + (size_t)(rowblk + lm)*H_ + lk;
    const __hip_bfloat16* hp1 = hprev + (size_t)(rowblk + 16 + lm)*H_ + lk;

    f32x4 acc[2][8];
#pragma unroll
    for (int i = 0; i < 2; ++i)
#pragma unroll
      for (int cb = 0; cb < 8; ++cb) acc[i][cb] = (f32x4)0.f;

    for (int ka = 0; ka < K1; ka += 32){
      bf16x8 a0h = *(const bf16x8*)(ap0 + ka);
      bf16x8 a0l = *(const bf16x8*)(ap0 + ka + DA);
      bf16x8 a1h = *(const bf16x8*)(ap1 + ka);
      bf16x8 a1l = *(const bf16x8*)(ap1 + ka + DA);
#pragma unroll
      for (int cb = 0; cb < 8; ++cb){
        bf16x8 bhv = *(const bf16x8*)(wp[cb] + ka);
        bf16x8 blv = *(const bf16x8*)(wp[cb] + ka + DW);
        acc[0][cb] = mfma16(a0h, bhv, acc[0][cb]);
        acc[0][cb] = mfma16(a0h, blv, acc[0][cb]);
        acc[0][cb] = mfma16(a0l, bhv, acc[0][cb]);
        acc[1][cb] = mfma16(a1h, bhv, acc[1][cb]);
        acc[1][cb] = mfma16(a1h, blv, acc[1][cb]);
        acc[1][cb] = mfma16(a1l, bhv, acc[1][cb]);
      }
    }
    if (t > 0){
      for (int kh = 0; kh < H_; kh += 32){
        bf16x8 a0h = *(const bf16x8*)(hp0 + kh);
        bf16x8 a0l = *(const bf16x8*)(hp0 + kh + DH4);
        bf16x8 a1h = *(const bf16x8*)(hp1 + kh);
        bf16x8 a1l = *(const bf16x8*)(hp1 + kh + DH4);
#pragma unroll
        for (int cb = 0; cb < 8; ++cb){
          bf16x8 bhv = *(const bf16x8*)(wp[cb] + K1 + kh);
          bf16x8 blv = *(const bf16x8*)(wp[cb] + K1 + kh + DW);
          acc[0][cb] = mfma16(a0h, bhv, acc[0][cb]);
          acc[0][cb] = mfma16(a0h, blv, acc[0][cb]);
          acc[0][cb] = mfma16(a0l, bhv, acc[0][cb]);
          acc[1][cb] = mfma16(a1h, bhv, acc[1][cb]);
          acc[1][cb] = mfma16(a1h, blv, acc[1][cb]);
          acc[1][cb] = mfma16(a1l, bhv, acc[1][cb]);
        }
      }
    }

#pragma unroll
    for (int i = 0; i < 2; ++i)
#pragma unroll
      for (int cb = 0; cb < 8; ++cb){
        int row = rowblk + i*16 + (lane >> 4)*4;
        int col = colblk + cb*16 + lm;
#pragma unroll
        for (int r = 0; r < 4; ++r) glds[row + r][col] = acc[i][cb][r];
      }
    __syncthreads();

    __hip_bfloat16* hout = hseq + (size_t)l*LSEQ + ((size_t)g*T_ + t)*B_*H_;
    for (int e = tid; e < 64*64; e += 256){
      int m = e >> 6, c = e & 63;
      int hcol = hc*64 + c;
      float gi = glds[m][c]       + bi[0*256+hcol] + bh[0*256+hcol];
      float gf = glds[m][64 + c]  + bi[1*256+hcol] + bh[1*256+hcol];
      float gg = glds[m][128 + c] + bi[2*256+hcol] + bh[2*256+hcol];
      float go = glds[m][192 + c] + bi[3*256+hcol] + bh[3*256+hcol];
      float cp = (t > 0) ? cbp[m*H_ + hcol] : 0.f;
      float c2 = sigm(gf)*cp + sigm(gi)*tanh_(gg);
      float h2 = sigm(go)*tanh_(c2);
      cbp[m*H_ + hcol] = c2;
      splitw(h2, hout + m*H_ + hcol, hout + DH4 + m*H_ + hcol);
    }
    __threadfence();
    __syncthreads();
    if (tid == 0) st_rel(&fe[grp*4 + hc], (unsigned int)(t+1));
  }
}

// ---------------- attention (hq.wa_h and attn_b cancel in softmax) --------------
__global__ __launch_bounds__(256) void k_attn(
  const __hip_bfloat16* hseq, const float* attnW, __hip_bfloat16* attn_bf)
{
  const int b = blockIdx.x; const int tid = threadIdx.x;
  const __hip_bfloat16* enc = hseq + (size_t)3*LSEQ;  // [gt][b][h]
  const float* wa_e = attnW + 256;
  __shared__ float sw[GT_];
  __shared__ float red[256];

  for (int it = 0; it < (GT_*4)/256; ++it){
    int idx = tid + it*256;
    int gt = idx >> 2, p = idx & 3;
    const __hip_bfloat16* ep = enc + ((size_t)gt*B_ + b)*H_ + p*64;
    float s = 0.f;
    for (int h = 0; h < 64; ++h) s += (b2f(ep[h]) + b2f(ep[h + DH4])) * wa_e[p*64 + h];
    s += __shfl_xor(s, 1);
    s += __shfl_xor(s, 2);
    if (p == 0) sw[gt] = s;
  }
  __syncthreads();
  float lmax = -1e30f;
  for (int idx = tid; idx < GT_; idx += 256) lmax = fmaxf(lmax, sw[idx]);
  red[tid] = lmax; __syncthreads();
  for (int s2 = 128; s2 > 0; s2 >>= 1){ if (tid < s2) red[tid] = fmaxf(red[tid], red[tid+s2]); __syncthreads(); }
  float M = red[0]; __syncthreads();
  float lsum = 0.f;
  for (int idx = tid; idx < GT_; idx += 256) lsum += __expf(sw[idx] - M);
  red[tid] = lsum; __syncthreads();
  for (int s2 = 128; s2 > 0; s2 >>= 1){ if (tid < s2) red[tid] += red[tid+s2]; __syncthreads(); }
  float Z = red[0]; __syncthreads();
  for (int idx = tid; idx < GT_; idx += 256) sw[idx] = __expf(sw[idx] - M) / Z;
  __syncthreads();
  float acc = 0.f;
  const __hip_bfloat16* ep = enc + (size_t)b*H_ + tid;
  for (int gt = 0; gt < GT_; ++gt){
    size_t o = (size_t)gt*B_*H_;
    acc += sw[gt] * (b2f(ep[o]) + b2f(ep[o + DH4]));
  }
  splitw(acc, attn_bf + b*H_ + tid, attn_bf + DAT + b*H_ + tid);
}

// ---------------- Gc[l][b][1024] = const gate part of decoder cells -------------
__global__ __launch_bounds__(256) void k_gc(
  const __hip_bfloat16* hseq, const __hip_bfloat16* attn_bf,
  const __hip_bfloat16* wb, const float* dbih, const float* dbhh,
  const int* p_to, float* Gc)
{
  const int to = *p_to;
  const int l = blockIdx.x >> 2, cb4 = blockIdx.x & 3;
  const int tid = threadIdx.x, wv = tid >> 6, lane = tid & 63;
  const int rowblk = (wv & 1)*32, colblk = (wv >> 1)*128;
  const int lm = lane & 15, lk = (lane >> 4)*8;
  const __hip_bfloat16* dech = hseq + (size_t)l*LSEQ + ((size_t)to*T_ + 63)*B_*H_;
  const __hip_bfloat16* W; int wstride;
  if (l == 0){ W = wb + OFF_GCW0; wstride = 512; }
  else { W = wb + OFF_GCW123 + (size_t)(l-1)*1024*256; wstride = 256; }
  const __hip_bfloat16* wp[8];
#pragma unroll
  for (int cb = 0; cb < 8; ++cb){
    int n = cb4*256 + colblk + cb*16 + lm;
    wp[cb] = W + (size_t)n*wstride + lk;
  }
  f32x4 acc[2][8];
#pragma unroll
  for (int i = 0; i < 2; ++i)
#pragma unroll
    for (int cb = 0; cb < 8; ++cb) acc[i][cb] = (f32x4)0.f;

  if (l == 0){
    const __hip_bfloat16* a0p = attn_bf + (size_t)(rowblk + lm)*H_ + lk;
    const __hip_bfloat16* a1p = attn_bf + (size_t)(rowblk + 16 + lm)*H_ + lk;
    for (int ka = 0; ka < 256; ka += 32){
      bf16x8 a0h = *(const bf16x8*)(a0p + ka);
      bf16x8 a0l = *(const bf16x8*)(a0p + ka + DAT);
      bf16x8 a1h = *(const bf16x8*)(a1p + ka);
      bf16x8 a1l = *(const bf16x8*)(a1p + ka + DAT);
#pragma unroll
      for (int cb = 0; cb < 8; ++cb){
        bf16x8 bh = *(const bf16x8*)(wp[cb] + ka);
        bf16x8 bl = *(const bf16x8*)(wp[cb] + ka + DW);
        acc[0][cb] = mfma16(a0h, bh, acc[0][cb]);
        acc[0][cb] = mfma16(a0h, bl, acc[0][cb]);
        acc[0][cb] = mfma16(a0l, bh, acc[0][cb]);
        acc[1][cb] = mfma16(a1h, bh, acc[1][cb]);
        acc[1][cb] = mfma16(a1h, bl, acc[1][cb]);
        acc[1][cb] = mfma16(a1l, bh, acc[1][cb]);
      }
    }
  }
  const int koff = (l == 0) ? 256 : 0;
  const __hip_bfloat16* h0p = dech + (size_t)(rowblk + lm)*H_ + lk;
  const __hip_bfloat16* h1p = dech + (size_t)(rowblk + 16 + lm)*H_ + lk;
  for (int ka = 0; ka < 256; ka += 32){
    bf16x8 a0h = *(const bf16x8*)(h0p + ka);
    bf16x8 a0l = *(const bf16x8*)(h0p + ka + DH4);
    bf16x8 a1h = *(const bf16x8*)(h1p + ka);
    bf16x8 a1l = *(const bf16x8*)(h1p + ka + DH4);
#pragma unroll
    for (int cb = 0; cb < 8; ++cb){
      bf16x8 bh = *(const bf16x8*)(wp[cb] + koff + ka);
      bf16x8 bl = *(const bf16x8*)(wp[cb] + koff + ka + DW);
      acc[0][cb] = mfma16(a0h, bh, acc[0][cb]);
      acc[0][cb] = mfma16(a0h, bl, acc[0][cb]);
      acc[0][cb] = mfma16(a0l, bh, acc[0][cb]);
      acc[1][cb] = mfma16(a1h, bh, acc[1][cb]);
      acc[1][cb] = mfma16(a1h, bl, acc[1][cb]);
      acc[1][cb] = mfma16(a1l, bh, acc[1][cb]);
    }
  }
#pragma unroll
  for (int i = 0; i < 2; ++i)
#pragma unroll
    for (int cb = 0; cb < 8; ++cb){
      int row = rowblk + i*16 + (lane >> 4)*4;
      int n = cb4*256 + colblk + cb*16 + lm;
#pragma unroll
      for (int r = 0; r < 4; ++r)
        Gc[((size_t)l*64 + (row + r))*NG + n] = acc[i][cb][r] + dbih[l*NG + n] + dbhh[l*NG + n];
    }
}

// ---------------- persistent decoder: 64 steps x 4 stages, store-based sync -----
// grid 48 = 12 row-tiles (16 chains) x 4 h-col tiles; block 256
__global__ __launch_bounds__(256) void k_dec(
  const float* x, const float* cbuf, const float* Gc, const __hip_bfloat16* wb,
  const float* dembW, const float* dembB,
  const float* outW, const float* outB,
  __hip_bfloat16* h2buf, float* dout, unsigned int* flags, const int* p_to)
{
  const int to = *p_to;
  const int rt = blockIdx.x >> 2, hc = blockIdx.x & 3;
  const int j = rt >> 2, b0 = (rt & 3)*16;
  const int R0 = rt*16;
  const int tid = threadIdx.x, wv = tid >> 6, lane = tid & 63;
  const int lm = lane & 15, lk = (lane >> 4)*8;
  unsigned int* slots = flags + rt*4;

  __shared__ float glds[16][256];
  __shared__ __hip_bfloat16 eldsH[16][136];
  __shared__ __hip_bfloat16 eldsL[16][136];
  __shared__ float outlds[16][4];
  unsigned int done = 0;

  // t=0 init: outlds from x
  if (tid < 64){
    int m = tid >> 2, f = tid & 3;
    outlds[m][f] = x[((size_t)((b0+m)*T_ + 63)*G_ + (to + j))*F_ + f];
  }
  __syncthreads();
  // e = relu(dec_emb(out_prev))
  for (int idx = tid; idx < 16*E_; idx += 256){
    int m = idx >> 7, ec = idx & 127;
    float s = dembB[ec];
#pragma unroll
    for (int f = 0; f < 4; ++f) s += outlds[m][f]*dembW[ec*4 + f];
    float e = fmaxf(s, 0.f);
    __hip_bfloat16 eh = __float2bfloat16(e);
    eldsH[m][ec] = eh;
    eldsL[m][ec] = __float2bfloat16(e - b2f(eh));
  }
  __syncthreads();

  for (int t = 0; t < T_; ++t){
    for (int l = 0; l < 4; ++l){
      const __hip_bfloat16* W; int wstride, Kt;
      if (l == 0){ W = wb + OFF_DWE; wstride = E_; Kt = E_; }
      else { W = wb + OFF_DWS + (size_t)(l-1)*1024*256; wstride = H_; Kt = H_; }
      const __hip_bfloat16* aptr = nullptr;
      if (l > 0){
        int rb = (l - 1) & 1;
        aptr = h2buf + (size_t)rb*192*H_ + (size_t)(R0 + lm)*H_ + lk;
      }
      const __hip_bfloat16* wp[4];
#pragma unroll
      for (int cb = 0; cb < 4; ++cb){
        int n = wv*256 + hc*64 + cb*16 + lm;
        wp[cb] = W + (size_t)n*wstride + lk;
      }
      f32x4 acc[4];
#pragma unroll
      for (int cb = 0; cb < 4; ++cb) acc[cb] = (f32x4)0.f;
      for (int ka = 0; ka < Kt; ka += 32){
        bf16x8 ah, al;
        if (l == 0){ ah = *(const bf16x8*)(&eldsH[lm][ka + lk]);
                     al = *(const bf16x8*)(&eldsL[lm][ka + lk]); }
        else { ah = *(const bf16x8*)(aptr + ka);
               al = *(const bf16x8*)(aptr + ka + DH2); }
#pragma unroll
        for (int cb = 0; cb < 4; ++cb){
          bf16x8 bh = *(const bf16x8*)(wp[cb] + ka);
          bf16x8 bl = *(const bf16x8*)(wp[cb] + ka + DW);
          acc[cb] = mfma16(ah, bh, acc[cb]);
          acc[cb] = mfma16(ah, bl, acc[cb]);
          acc[cb] = mfma16(al, bh, acc[cb]);
        }
      }
#pragma unroll
      for (int cb = 0; cb < 4; ++cb){
        int row = (lane >> 4)*4, col = wv*64 + cb*16 + lm;
#pragma unroll
        for (int r = 0; r < 4; ++r) glds[row + r][col] = acc[cb][r];
      }
      __syncthreads();

      int wb2 = l & 1;
      __hip_bfloat16* hout = h2buf + (size_t)wb2*192*H_;
      const float* cf = cbuf + ((size_t)l*G_ + to)*B_*H_;
      const float* gcl = Gc + (size_t)l*64*NG;
      for (int idx = tid; idx < 16*64; idx += 256){
        int m = idx >> 6, c = idx & 63;
        int hcol = hc*64 + c; int b = b0 + m;
        float gi = glds[m][c]       + gcl[b*NG + 0*256 + hcol];
        float gf = glds[m][64 + c]  + gcl[b*NG + 1*256 + hcol];
        float gg = glds[m][128 + c] + gcl[b*NG + 2*256 + hcol];
        float go = glds[m][192 + c] + gcl[b*NG + 3*256 + hcol];
        float cp = cf[b*H_ + hcol];
        float c2 = sigm(gf)*cp + sigm(gi)*tanh_(gg);
        float h2v = sigm(go)*tanh_(c2);
        size_t oo = (size_t)(R0 + m)*H_ + hcol;
        __hip_bfloat16 hh = __float2bfloat16(h2v);
        hout[oo] = hh;
        hout[oo + DH2] = __float2bfloat16(h2v - b2f(hh));
      }
      // group sync: store own slot, poll all 4
      __threadfence();
      __syncthreads();
      done++;
      if (tid == 0) st_rel(&slots[hc], done);
      if (tid < 4){
        while (ld_acq(&slots[tid]) < done) __builtin_amdgcn_s_sleep(1);
      }
      __syncthreads();
    }

    // post-L3: out-GEMM (parallel, vectorized) + dout write + next-step e
    {
      int m = tid >> 4, sub = tid & 15, f = sub & 3, kq = sub >> 2;
      const __hip_bfloat16* hp = h2buf + (size_t)192*H_ + (size_t)(R0 + m)*H_ + kq*64;
      const float* owp = outW + f*H_ + kq*64;
      float s = 0.f;
#pragma unroll
      for (int i = 0; i < 8; ++i){
        bf16x8 hh = *(const bf16x8*)(hp + i*8);
        bf16x8 hl = *(const bf16x8*)(hp + i*8 + DH2);
        const float4 w0 = *(const float4*)(owp + i*8);
        const float4 w1 = *(const float4*)(owp + i*8 + 4);
        s += (s2f(hh[0])+s2f(hl[0]))*w0.x; s += (s2f(hh[1])+s2f(hl[1]))*w0.y;
        s += (s2f(hh[2])+s2f(hl[2]))*w0.z; s += (s2f(hh[3])+s2f(hl[3]))*w0.w;
        s += (s2f(hh[4])+s2f(hl[4]))*w1.x; s += (s2f(hh[5])+s2f(hl[5]))*w1.y;
        s += (s2f(hh[6])+s2f(hl[6]))*w1.z; s += (s2f(hh[7])+s2f(hl[7]))*w1.w;
      }
      s += __shfl_xor(s, 4);
      s += __shfl_xor(s, 8);
      if (kq == 0){
        float ov = s + outB[f];
        outlds[m][f] = ov;
        if (hc == 0) dout[(((size_t)(b0+m)*T_ + t)*3 + j)*F_ + f] = ov;
      }
    }
    __syncthreads();
    if (t < T_-1){
      for (int idx = tid; idx < 16*E_; idx += 256){
        int m = idx >> 7, ec = idx & 127;
        float s = dembB[ec];
#pragma unroll
        for (int f = 0; f < 4; ++f) s += outlds[m][f]*dembW[ec*4 + f];
        float e = fmaxf(s, 0.f);
        __hip_bfloat16 eh = __float2bfloat16(e);
        eldsH[m][ec] = eh;
        eldsL[m][ec] = __float2bfloat16(e - b2f(eh));
      }
      __syncthreads();
    }
  }
}

extern "C" void kernel_launch(void* const* d_in, const int* in_sizes, int n_in,
                              void* d_out, int out_size, void* d_ws, size_t ws_size,
                              hipStream_t stream)
{
  const float* x         = (const float*)d_in[0];
  const float* enc_lin_W = (const float*)d_in[2];
  const float* enc_lin_b = (const float*)d_in[3];
  const float* enc_Wih0  = (const float*)d_in[4];
  const float* enc_Wihs  = (const float*)d_in[5];
  const float* enc_Whh   = (const float*)d_in[6];
  const float* enc_bih   = (const float*)d_in[7];
  const float* enc_bhh   = (const float*)d_in[8];
  const float* dec_emb_W = (const float*)d_in[9];
  const float* dec_emb_b = (const float*)d_in[10];
  const float* attn_W    = (const float*)d_in[11];
  const float* dec_Wih0  = (const float*)d_in[13];
  const float* dec_Wihs  = (const float*)d_in[14];
  const float* dec_Whh   = (const float*)d_in[15];
  const float* dec_bih   = (const float*)d_in[16];
  const float* dec_bhh   = (const float*)d_in[17];
  const float* out_W     = (const float*)d_in[18];
  const float* out_b     = (const float*)d_in[19];
  const int*   p_to      = (const int*)d_in[20];
  float* dout = (float*)d_out;
  (void)in_sizes; (void)n_in; (void)out_size; (void)ws_size;

  char* ws = (char*)d_ws;
  size_t off = 0;
  auto take = [&](size_t nbytes) -> void* {
    void* p = ws + off; off += (nbytes + 255) & ~(size_t)255; return p; };
  __hip_bfloat16* hseq    = (__hip_bfloat16*)take((size_t)8*LSEQ*2);          // H+L
  __hip_bfloat16* emb     = (__hip_bfloat16*)take((size_t)2*G_*T_*B_*E_*2);   // H+L
  float*          cbuf    = (float*)take((size_t)4*G_*B_*H_*4);
  __hip_bfloat16* wblob   = (__hip_bfloat16*)take((size_t)2*WBLOB_N*2);       // H+L
  __hip_bfloat16* attn_bf = (__hip_bfloat16*)take((size_t)2*64*256*2);        // H+L
  float*          Gc      = (float*)take((size_t)4*64*1024*4);
  __hip_bfloat16* h2buf   = (__hip_bfloat16*)take((size_t)2*2*192*256*2);     // H+L
  unsigned int*   flags   = (unsigned int*)take(1024);
  unsigned int*   fenc    = flags;          // 176 slots
  unsigned int*   fdec    = flags + 176;    // 48 slots

  hipMemsetAsync(flags, 0, 1024, stream);
  k_conv<<<2048, 256, 0, stream>>>(enc_Wih0, enc_Wihs, enc_Whh, dec_Wih0, dec_Wihs, dec_Whh, wblob);
  k_emb<<<2048, 256, 0, stream>>>(x, enc_lin_W, enc_lin_b, emb);
  k_enc_p<<<176, 256, 0, stream>>>(hseq, emb, cbuf, wblob, enc_bih, enc_bhh, fenc);
  k_attn<<<64, 256, 0, stream>>>(hseq, attn_W, attn_bf);
  k_gc<<<16, 256, 0, stream>>>(hseq, attn_bf, wblob, dec_bih, dec_bhh, p_to, Gc);
  k_dec<<<48, 256, 0, stream>>>(x, cbuf, Gc, wblob, dec_emb_W, dec_emb_b, out_W, out_b,
                                h2buf, dout, fdec, p_to);
}

// Round 6
// 8815.665 us; speedup vs baseline: 1.0686x; 1.0686x over previous
//
#include <hip/hip_runtime.h>
#include <hip/hip_bf16.h>
#include <stdint.h>

#define B_ 64
#define T_ 64
#define G_ 11
#define F_ 4
#define E_ 128
#define H_ 256
#define NG 1024
#define GT_ 704

// weight blob region offsets (elements); lo-copy at +DW
#define OFF_WCAT0   0
#define OFF_WCAT123 393216
#define OFF_GCW0    1966080
#define OFF_GCW123  2490368
#define OFF_DWE     3276800
#define OFF_DWS     3407872
#define WBLOB_N     4194304
#define DW  ((size_t)WBLOB_N)
#define DE  ((size_t)5767168)     // emb lo-offset
#define DAT ((size_t)16384)       // attn lo-offset

typedef __attribute__((ext_vector_type(8))) short bf16x8;
typedef __attribute__((ext_vector_type(4))) float f32x4;
typedef __attribute__((ext_vector_type(4))) unsigned int u32x4;

__device__ __forceinline__ f32x4 mfma16(bf16x8 a, bf16x8 b, f32x4 c){
  return __builtin_amdgcn_mfma_f32_16x16x32_bf16(a, b, c, 0, 0, 0);
}
__device__ __forceinline__ float sigm(float x){ return 1.f/(1.f+__expf(-x)); }
__device__ __forceinline__ float tanh_(float x){ float e=__expf(2.f*x); return 1.f - 2.f/(e+1.f); }
__device__ __forceinline__ float b2f(__hip_bfloat16 v){ return __bfloat162float(v); }
__device__ __forceinline__ void splitw(float v, __hip_bfloat16* ph, __hip_bfloat16* pl){
  __hip_bfloat16 h = __float2bfloat16(v);
  *ph = h; *pl = __float2bfloat16(v - __bfloat162float(h));
}
// bf16 round-to-nearest-even bits
__device__ __forceinline__ unsigned int f2b(float f){
  unsigned int u = __float_as_uint(f);
  return (u + 0x7fffu + ((u>>16)&1u)) >> 16;
}
__device__ __forceinline__ unsigned int packsplit(float v){
  unsigned int hb = f2b(v);
  float hf = __uint_as_float(hb<<16);
  unsigned int lb = f2b(v - hf);
  return (hb<<16) | lb;
}
__device__ __forceinline__ float up_f(unsigned int u){
  return __uint_as_float(u & 0xffff0000u) + __uint_as_float(u << 16);
}
// relaxed (UC) atomics: bypass caches, never invalidate L2
__device__ __forceinline__ unsigned int ld_na(const unsigned int* p){
  return __hip_atomic_load(p, __ATOMIC_RELAXED, __HIP_MEMORY_SCOPE_AGENT);
}
__device__ __forceinline__ void st_na(unsigned int* p, unsigned int v){
  __hip_atomic_store(p, v, __ATOMIC_RELAXED, __HIP_MEMORY_SCOPE_AGENT);
}

// unpack 8 packed u32 (two u32x4) -> hi/lo bf16x8
#define UNPK8(pa, pb, h8, l8) \
  { _Pragma("unroll") for (int q2_ = 0; q2_ < 4; ++q2_){ \
      h8[q2_]   = (short)(pa[q2_] >> 16); l8[q2_]   = (short)(pa[q2_] & 0xffffu); \
      h8[4+q2_] = (short)(pb[q2_] >> 16); l8[4+q2_] = (short)(pb[q2_] & 0xffffu); } }

// ---------------- weight conversion fp32 -> split bf16 (hi/lo blobs) -----------
__global__ void k_conv(const float* Wih0, const float* Wihs, const float* Whh,
                       const float* dWih0, const float* dWihs, const float* dWhh,
                       __hip_bfloat16* out)
{
  for (int i = blockIdx.x*blockDim.x + threadIdx.x; i < WBLOB_N; i += gridDim.x*blockDim.x){
    int j = i; float v;
    if (j < 393216) {                       // Wcat0 [1024][384]
      int n = j/384, k = j%384;
      v = (k<128) ? Wih0[n*128+k] : Whh[n*256 + (k-128)];
    } else if ((j -= 393216) < 1572864) {   // Wcat123 3x[1024][512]
      int l = j/524288; int r = j%524288; int n = r/512, k = r%512;
      v = (k<256) ? Wihs[(l*1024+n)*256+k] : Whh[((l+1)*1024+n)*256 + (k-256)];
    } else if ((j -= 1572864) < 524288) {   // GcW0 [1024][512]
      int n = j/512, k = j%512;
      v = (k<256) ? dWih0[n*384+k] : dWhh[n*256 + (k-256)];
    } else if ((j -= 524288) < 786432) {    // GcW123 3x[1024][256]
      int l = j/262144; int r = j%262144; int n = r/256, k = r%256;
      v = dWhh[((l+1)*1024+n)*256+k];
    } else if ((j -= 786432) < 131072) {    // dWe [1024][128]
      int n = j/128, k = j%128;
      v = dWih0[n*384 + 256 + k];
    } else { j -= 131072; v = dWihs[j]; }   // dWs 3x[1024][256]
    splitw(v, out + i, out + i + DW);
  }
}

// ---------------- emb = relu(xg @ enc_lin_W^T + b), split bf16 ------------------
__global__ void k_emb(const float* x, const float* W, const float* bb, __hip_bfloat16* emb)
{
  const int N = G_*T_*B_*E_;
  for (int i = blockIdx.x*blockDim.x + threadIdx.x; i < N; i += gridDim.x*blockDim.x){
    int e = i & 127; int row = i >> 7;
    int b = row & 63; int t = (row >> 6) & 63; int g = row >> 12;
    const float* xp = x + ((size_t)(b*T_ + t)*G_ + g)*F_;
    float s = bb[e];
#pragma unroll
    for (int f = 0; f < 4; ++f) s += xp[f]*W[e*4+f];
    splitw(fmaxf(s, 0.f), emb + i, emb + i + DE);
  }
}

// ---------------- persistent encoder: bid=g*16+l*4+hc, loops t=0..63 ------------
// h exchanged via packed-u32 relaxed atomics; c-state in registers; no acquire.
__global__ __launch_bounds__(256) void k_enc_p(
  unsigned int* hpk, const __hip_bfloat16* emb, float* cbuf,
  const __hip_bfloat16* wb, const float* bih, const float* bhh,
  unsigned int* fe, const int* p_to)
{
  const int bid = blockIdx.x;
  const int g = bid >> 4, l = (bid >> 2) & 3, hc = bid & 3;
  const int grp = l*G_ + g, pgrp = grp - G_;
  const int to = *p_to;
  const int tid = threadIdx.x, wv = tid >> 6, lane = tid & 63;
  const int rowblk = (wv & 1)*32, hcb = (wv >> 1)*32;
  const int lm = lane & 15, lk = (lane >> 4)*8;

  const __hip_bfloat16* W; int wstride, K1;
  if (l == 0){ W = wb + OFF_WCAT0; wstride = 384; K1 = E_; }
  else { W = wb + OFF_WCAT123 + (size_t)(l-1)*1024*512; wstride = 512; K1 = H_; }

  // wave owns h-cols hc*64+hcb..+31, all 4 gates: cb = q*2+sub
  const __hip_bfloat16* wp[8];
#pragma unroll
  for (int cb = 0; cb < 8; ++cb){
    int q = cb >> 1, sub = cb & 1;
    int n = q*256 + hc*64 + hcb + sub*16 + lm;
    wp[cb] = W + (size_t)n*wstride + lk;
  }
  float bsum[2][4];
#pragma unroll
  for (int sub = 0; sub < 2; ++sub)
#pragma unroll
    for (int q = 0; q < 4; ++q){
      int colg = q*256 + hc*64 + hcb + sub*16 + lm;
      bsum[sub][q] = bih[l*NG + colg] + bhh[l*NG + colg];
    }
  float creg[2][2][4];
#pragma unroll
  for (int i = 0; i < 2; ++i)
#pragma unroll
    for (int s = 0; s < 2; ++s)
#pragma unroll
      for (int r = 0; r < 4; ++r) creg[i][s][r] = 0.f;

  unsigned int* hpl = hpk + (size_t)grp*T_*B_*H_;
  const unsigned int* xsrc = (l > 0) ? (hpk + (size_t)pgrp*T_*B_*H_) : nullptr;

  __shared__ unsigned int pk[64][256];

  for (int t = 0; t < T_; ++t){
    if (t > 0 && tid < 4){
      while (ld_na(&fe[grp*4 + tid]) < (unsigned int)t) __builtin_amdgcn_s_sleep(1);
    }
    if (l > 0 && tid >= 4 && tid < 8){
      while (ld_na(&fe[pgrp*4 + (tid-4)]) < (unsigned int)(t+1)) __builtin_amdgcn_s_sleep(1);
    }
    __syncthreads();

    f32x4 acc[2][8];
#pragma unroll
    for (int i = 0; i < 2; ++i)
#pragma unroll
      for (int cb = 0; cb < 8; ++cb) acc[i][cb] = (f32x4)0.f;

    // ---- phase A: x-input GEMM ----
    if (l == 0){
      const __hip_bfloat16* xin = emb + ((size_t)g*T_ + t)*B_*E_;
      const __hip_bfloat16* ap0 = xin + (size_t)(rowblk + lm)*E_ + lk;
      const __hip_bfloat16* ap1 = xin + (size_t)(rowblk + 16 + lm)*E_ + lk;
      for (int ka = 0; ka < E_; ka += 32){
        bf16x8 a0h = *(const bf16x8*)(ap0 + ka);
        bf16x8 a0l = *(const bf16x8*)(ap0 + ka + DE);
        bf16x8 a1h = *(const bf16x8*)(ap1 + ka);
        bf16x8 a1l = *(const bf16x8*)(ap1 + ka + DE);
#pragma unroll
        for (int cb = 0; cb < 8; ++cb){
          bf16x8 bh = *(const bf16x8*)(wp[cb] + ka);
          bf16x8 bl = *(const bf16x8*)(wp[cb] + ka + DW);
          acc[0][cb] = mfma16(a0h, bh, acc[0][cb]);
          acc[0][cb] = mfma16(a0h, bl, acc[0][cb]);
          acc[0][cb] = mfma16(a0l, bh, acc[0][cb]);
          acc[1][cb] = mfma16(a1h, bh, acc[1][cb]);
          acc[1][cb] = mfma16(a1h, bl, acc[1][cb]);
          acc[1][cb] = mfma16(a1l, bh, acc[1][cb]);
        }
      }
    } else {
      const unsigned int* src = xsrc + (size_t)t*B_*H_;
      for (int i = tid; i < 16384; i += 256){
        int r = i >> 8, c = i & 255;
        pk[r][c ^ ((r & 7) << 2)] = ld_na(src + i);
      }
      __syncthreads();
      for (int ks = 0; ks < 8; ++ks){
        int K0 = ks*32 + lk;
        bf16x8 a0h,a0l,a1h,a1l;
        { int R = rowblk + lm, sw = (R & 7) << 2;
          u32x4 pa = *(const u32x4*)&pk[R][(K0) ^ sw];
          u32x4 pb = *(const u32x4*)&pk[R][(K0+4) ^ sw];
          UNPK8(pa, pb, a0h, a0l); }
        { int R = rowblk + 16 + lm, sw = (R & 7) << 2;
          u32x4 pa = *(const u32x4*)&pk[R][(K0) ^ sw];
          u32x4 pb = *(const u32x4*)&pk[R][(K0+4) ^ sw];
          UNPK8(pa, pb, a1h, a1l); }
#pragma unroll
        for (int cb = 0; cb < 8; ++cb){
          bf16x8 bh = *(const bf16x8*)(wp[cb] + ks*32);
          bf16x8 bl = *(const bf16x8*)(wp[cb] + ks*32 + DW);
          acc[0][cb] = mfma16(a0h, bh, acc[0][cb]);
          acc[0][cb] = mfma16(a0h, bl, acc[0][cb]);
          acc[0][cb] = mfma16(a0l, bh, acc[0][cb]);
          acc[1][cb] = mfma16(a1h, bh, acc[1][cb]);
          acc[1][cb] = mfma16(a1h, bl, acc[1][cb]);
          acc[1][cb] = mfma16(a1l, bh, acc[1][cb]);
        }
      }
      __syncthreads();
    }
    // ---- phase B: recurrent GEMM ----
    if (t > 0){
      const unsigned int* src = hpl + (size_t)(t-1)*B_*H_;
      for (int i = tid; i < 16384; i += 256){
        int r = i >> 8, c = i & 255;
        pk[r][c ^ ((r & 7) << 2)] = ld_na(src + i);
      }
      __syncthreads();
      for (int ks = 0; ks < 8; ++ks){
        int K0 = ks*32 + lk;
        bf16x8 a0h,a0l,a1h,a1l;
        { int R = rowblk + lm, sw = (R & 7) << 2;
          u32x4 pa = *(const u32x4*)&pk[R][(K0) ^ sw];
          u32x4 pb = *(const u32x4*)&pk[R][(K0+4) ^ sw];
          UNPK8(pa, pb, a0h, a0l); }
        { int R = rowblk + 16 + lm, sw = (R & 7) << 2;
          u32x4 pa = *(const u32x4*)&pk[R][(K0) ^ sw];
          u32x4 pb = *(const u32x4*)&pk[R][(K0+4) ^ sw];
          UNPK8(pa, pb, a1h, a1l); }
#pragma unroll
        for (int cb = 0; cb < 8; ++cb){
          bf16x8 bh = *(const bf16x8*)(wp[cb] + K1 + ks*32);
          bf16x8 bl = *(const bf16x8*)(wp[cb] + K1 + ks*32 + DW);
          acc[0][cb] = mfma16(a0h, bh, acc[0][cb]);
          acc[0][cb] = mfma16(a0h, bl, acc[0][cb]);
          acc[0][cb] = mfma16(a0l, bh, acc[0][cb]);
          acc[1][cb] = mfma16(a1h, bh, acc[1][cb]);
          acc[1][cb] = mfma16(a1h, bl, acc[1][cb]);
          acc[1][cb] = mfma16(a1l, bh, acc[1][cb]);
        }
      }
    }

    // ---- register epilogue: gates -> h,c; pack+UC-store h ----
    unsigned int* hdst = hpl + (size_t)t*B_*H_;
#pragma unroll
    for (int i = 0; i < 2; ++i)
#pragma unroll
      for (int sub = 0; sub < 2; ++sub)
#pragma unroll
        for (int r = 0; r < 4; ++r){
          float gi = acc[i][0+sub][r] + bsum[sub][0];
          float gf = acc[i][2+sub][r] + bsum[sub][1];
          float gg = acc[i][4+sub][r] + bsum[sub][2];
          float go = acc[i][6+sub][r] + bsum[sub][3];
          float cp = creg[i][sub][r];
          float c2 = sigm(gf)*cp + sigm(gi)*tanh_(gg);
          float h2 = sigm(go)*tanh_(c2);
          creg[i][sub][r] = c2;
          int row = rowblk + i*16 + (lane >> 4)*4 + r;
          int col = hc*64 + hcb + sub*16 + lm;
          st_na(hdst + (size_t)row*H_ + col, packsplit(h2));
          if (t == T_-1 && g == to)
            cbuf[(size_t)(l*G_ + g)*B_*H_ + row*H_ + col] = c2;
        }
    __syncthreads();   // drains each wave's UC stores (vmcnt 0 before s_barrier)
    if (tid == 0) st_na(&fe[grp*4 + hc], (unsigned int)(t+1));
  }
}

// ---------------- attention (hq.wa_h and attn_b cancel in softmax) --------------
__global__ __launch_bounds__(256) void k_attn(
  const unsigned int* hpk, const float* attnW, __hip_bfloat16* attn_bf)
{
  const int b = blockIdx.x; const int tid = threadIdx.x;
  const unsigned int* enc = hpk + (size_t)3*G_*T_*B_*H_;   // [gt][b][h] packed
  const float* wa_e = attnW + 256;
  __shared__ float sw_[GT_];
  __shared__ float red[256];

  for (int it = 0; it < (GT_*4)/256; ++it){
    int idx = tid + it*256;
    int gt = idx >> 2, p = idx & 3;
    const unsigned int* ep = enc + ((size_t)gt*B_ + b)*H_ + p*64;
    float s = 0.f;
    for (int h = 0; h < 64; ++h) s += up_f(ep[h]) * wa_e[p*64 + h];
    s += __shfl_xor(s, 1);
    s += __shfl_xor(s, 2);
    if (p == 0) sw_[gt] = s;
  }
  __syncthreads();
  float lmax = -1e30f;
  for (int idx = tid; idx < GT_; idx += 256) lmax = fmaxf(lmax, sw_[idx]);
  red[tid] = lmax; __syncthreads();
  for (int s2 = 128; s2 > 0; s2 >>= 1){ if (tid < s2) red[tid] = fmaxf(red[tid], red[tid+s2]); __syncthreads(); }
  float M = red[0]; __syncthreads();
  float lsum = 0.f;
  for (int idx = tid; idx < GT_; idx += 256) lsum += __expf(sw_[idx] - M);
  red[tid] = lsum; __syncthreads();
  for (int s2 = 128; s2 > 0; s2 >>= 1){ if (tid < s2) red[tid] += red[tid+s2]; __syncthreads(); }
  float Z = red[0]; __syncthreads();
  for (int idx = tid; idx < GT_; idx += 256) sw_[idx] = __expf(sw_[idx] - M) / Z;
  __syncthreads();
  float acc = 0.f;
  const unsigned int* ep = enc + (size_t)b*H_ + tid;
  for (int gt = 0; gt < GT_; ++gt) acc += sw_[gt] * up_f(ep[(size_t)gt*B_*H_]);
  splitw(acc, attn_bf + b*H_ + tid, attn_bf + DAT + b*H_ + tid);
}

// ---------------- Gc[l][b][1024] = const gate part of decoder cells -------------
__global__ __launch_bounds__(256) void k_gc(
  const unsigned int* hpk, const __hip_bfloat16* attn_bf,
  const __hip_bfloat16* wb, const float* dbih, const float* dbhh,
  const int* p_to, float* Gc)
{
  const int to = *p_to;
  const int l = blockIdx.x >> 2, cb4 = blockIdx.x & 3;
  const int tid = threadIdx.x, wv = tid >> 6, lane = tid & 63;
  const int rowblk = (wv & 1)*32, colblk = (wv >> 1)*128;
  const int lm = lane & 15, lk = (lane >> 4)*8;
  const unsigned int* dech = hpk + ((size_t)(l*G_ + to)*T_ + 63)*B_*H_;
  const __hip_bfloat16* W; int wstride;
  if (l == 0){ W = wb + OFF_GCW0; wstride = 512; }
  else { W = wb + OFF_GCW123 + (size_t)(l-1)*1024*256; wstride = 256; }
  const __hip_bfloat16* wp[8];
#pragma unroll
  for (int cb = 0; cb < 8; ++cb){
    int n = cb4*256 + colblk + cb*16 + lm;
    wp[cb] = W + (size_t)n*wstride + lk;
  }
  f32x4 acc[2][8];
#pragma unroll
  for (int i = 0; i < 2; ++i)
#pragma unroll
    for (int cb = 0; cb < 8; ++cb) acc[i][cb] = (f32x4)0.f;

  if (l == 0){
    const __hip_bfloat16* a0p = attn_bf + (size_t)(rowblk + lm)*H_ + lk;
    const __hip_bfloat16* a1p = attn_bf + (size_t)(rowblk + 16 + lm)*H_ + lk;
    for (int ka = 0; ka < 256; ka += 32){
      bf16x8 a0h = *(const bf16x8*)(a0p + ka);
      bf16x8 a0l = *(const bf16x8*)(a0p + ka + DAT);
      bf16x8 a1h = *(const bf16x8*)(a1p + ka);
      bf16x8 a1l = *(const bf16x8*)(a1p + ka + DAT);
#pragma unroll
      for (int cb = 0; cb < 8; ++cb){
        bf16x8 bh = *(const bf16x8*)(wp[cb] + ka);
        bf16x8 bl = *(const bf16x8*)(wp[cb] + ka + DW);
        acc[0][cb] = mfma16(a0h, bh, acc[0][cb]);
        acc[0][cb] = mfma16(a0h, bl, acc[0][cb]);
        acc[0][cb] = mfma16(a0l, bh, acc[0][cb]);
        acc[1][cb] = mfma16(a1h, bh, acc[1][cb]);
        acc[1][cb] = mfma16(a1h, bl, acc[1][cb]);
        acc[1][cb] = mfma16(a1l, bh, acc[1][cb]);
      }
    }
  }
  const int koff = (l == 0) ? 256 : 0;
  for (int ka = 0; ka < 256; ka += 32){
    bf16x8 a0h,a0l,a1h,a1l;
    { const unsigned int* p0 = dech + (size_t)(rowblk + lm)*H_ + ka + lk;
      u32x4 pa = *(const u32x4*)p0; u32x4 pb = *(const u32x4*)(p0 + 4);
      UNPK8(pa, pb, a0h, a0l); }
    { const unsigned int* p1 = dech + (size_t)(rowblk + 16 + lm)*H_ + ka + lk;
      u32x4 pa = *(const u32x4*)p1; u32x4 pb = *(const u32x4*)(p1 + 4);
      UNPK8(pa, pb, a1h, a1l); }
#pragma unroll
    for (int cb = 0; cb < 8; ++cb){
      bf16x8 bh = *(const bf16x8*)(wp[cb] + koff + ka);
      bf16x8 bl = *(const bf16x8*)(wp[cb] + koff + ka + DW);
      acc[0][cb] = mfma16(a0h, bh, acc[0][cb]);
      acc[0][cb] = mfma16(a0h, bl, acc[0][cb]);
      acc[0][cb] = mfma16(a0l, bh, acc[0][cb]);
      acc[1][cb] = mfma16(a1h, bh, acc[1][cb]);
      acc[1][cb] = mfma16(a1h, bl, acc[1][cb]);
      acc[1][cb] = mfma16(a1l, bh, acc[1][cb]);
    }
  }
#pragma unroll
  for (int i = 0; i < 2; ++i)
#pragma unroll
    for (int cb = 0; cb < 8; ++cb){
      int row = rowblk + i*16 + (lane >> 4)*4;
      int n = cb4*256 + colblk + cb*16 + lm;
#pragma unroll
      for (int r = 0; r < 4; ++r)
        Gc[((size_t)l*64 + (row + r))*NG + n] = acc[i][cb][r] + dbih[l*NG + n] + dbhh[l*NG + n];
    }
}

// ---------------- persistent decoder: relaxed-atomic sync, register epilogue ----
// grid 48 = 12 row-tiles (16 chains) x 4 h-col tiles; block 256
__global__ __launch_bounds__(256) void k_dec(
  const float* x, const float* cbuf, const float* Gc, const __hip_bfloat16* wb,
  const float* dembW, const float* dembB,
  const float* outW, const float* outB,
  unsigned int* hpk2, float* dout, unsigned int* flags, const int* p_to)
{
  const int to = *p_to;
  const int rt = blockIdx.x >> 2, hc = blockIdx.x & 3;
  const int j = rt >> 2, b0 = (rt & 3)*16;
  const int R0 = rt*16;
  const int tid = threadIdx.x, wv = tid >> 6, lane = tid & 63;
  const int lm = lane & 15, lk = (lane >> 4)*8;
  const int myc = hc*64 + wv*16 + lm;     // h-col this lane owns
  const int m_  = (lane >> 4)*4;          // row base (r=0..3)
  unsigned int* slots = flags + rt*4;

  // hoist frozen Gc and c into registers (read once)
  float gc[4][4][4];   // [l][q][r]
  float cp[4][4];      // [l][r]
#pragma unroll
  for (int l = 0; l < 4; ++l){
#pragma unroll
    for (int r = 0; r < 4; ++r){
      cp[l][r] = cbuf[((size_t)l*G_ + to)*B_*H_ + (size_t)(b0 + m_ + r)*H_ + myc];
#pragma unroll
      for (int q = 0; q < 4; ++q)
        gc[l][q][r] = Gc[((size_t)l*64 + (b0 + m_ + r))*NG + q*256 + myc];
    }
  }

  __shared__ unsigned int dpk[16][256];
  __shared__ __hip_bfloat16 eldsH[16][136];
  __shared__ __hip_bfloat16 eldsL[16][136];
  __shared__ float outlds[16][4];
  unsigned int done = 0;

  // t=0: outlds from x, then elds
  if (tid < 64){
    int m = tid >> 2, f = tid & 3;
    outlds[m][f] = x[((size_t)((b0+m)*T_ + 63)*G_ + (to + j))*F_ + f];
  }
  __syncthreads();
  for (int idx = tid; idx < 16*E_; idx += 256){
    int m = idx >> 7, ec = idx & 127;
    float s = dembB[ec];
#pragma unroll
    for (int f = 0; f < 4; ++f) s += outlds[m][f]*dembW[ec*4 + f];
    float e = fmaxf(s, 0.f);
    __hip_bfloat16 eh = __float2bfloat16(e);
    eldsH[m][ec] = eh;
    eldsL[m][ec] = __float2bfloat16(e - b2f(eh));
  }
  __syncthreads();

  for (int t = 0; t < T_; ++t){
    for (int l = 0; l < 4; ++l){
      if (l > 0){
        const unsigned int* src = hpk2 + (size_t)((l-1)&1)*192*H_ + (size_t)R0*H_;
        for (int i = tid; i < 4096; i += 256){
          int r = i >> 8, c = i & 255;
          dpk[r][c ^ ((r & 7) << 2)] = ld_na(src + i);
        }
        __syncthreads();
      }
      const __hip_bfloat16* W; int wstride, ksteps;
      if (l == 0){ W = wb + OFF_DWE; wstride = E_; ksteps = 4; }
      else { W = wb + OFF_DWS + (size_t)(l-1)*1024*256; wstride = H_; ksteps = 8; }
      const __hip_bfloat16* wpd[4];
#pragma unroll
      for (int q = 0; q < 4; ++q)
        wpd[q] = W + (size_t)(q*256 + myc)*wstride + lk;

      f32x4 acc[4];
#pragma unroll
      for (int q = 0; q < 4; ++q) acc[q] = (f32x4)0.f;

      for (int ks = 0; ks < ksteps; ++ks){
        bf16x8 ah, al;
        if (l == 0){
          ah = *(const bf16x8*)(&eldsH[lm][ks*32 + lk]);
          al = *(const bf16x8*)(&eldsL[lm][ks*32 + lk]);
        } else {
          int K0 = ks*32 + lk, sw = (lm & 7) << 2;
          u32x4 pa = *(const u32x4*)&dpk[lm][(K0) ^ sw];
          u32x4 pb = *(const u32x4*)&dpk[lm][(K0+4) ^ sw];
          UNPK8(pa, pb, ah, al);
        }
#pragma unroll
        for (int q = 0; q < 4; ++q){
          bf16x8 bh = *(const bf16x8*)(wpd[q] + ks*32);
          bf16x8 bl = *(const bf16x8*)(wpd[q] + ks*32 + DW);
          acc[q] = mfma16(ah, bh, acc[q]);
          acc[q] = mfma16(ah, bl, acc[q]);
          acc[q] = mfma16(al, bh, acc[q]);
        }
      }
      // register epilogue
      unsigned int* hdst = hpk2 + (size_t)(l&1)*192*H_;
#pragma unroll
      for (int r = 0; r < 4; ++r){
        float gi = acc[0][r] + gc[l][0][r];
        float gf = acc[1][r] + gc[l][1][r];
        float gg = acc[2][r] + gc[l][2][r];
        float go = acc[3][r] + gc[l][3][r];
        float c2 = sigm(gf)*cp[l][r] + sigm(gi)*tanh_(gg);
        float h2v = sigm(go)*tanh_(c2);
        st_na(hdst + (size_t)(R0 + m_ + r)*H_ + myc, packsplit(h2v));
      }
      __syncthreads();   // drains UC stores
      done++;
      if (tid == 0) st_na(&slots[hc], done);
      if (tid < 4){
        while (ld_na(&slots[tid]) < done) __builtin_amdgcn_s_sleep(1);
      }
      __syncthreads();
    }

    // stage h(3) and do out-GEMM + dout + next-step elds
    {
      const unsigned int* src = hpk2 + (size_t)1*192*H_ + (size_t)R0*H_;
      for (int i = tid; i < 4096; i += 256){
        int r = i >> 8, c = i & 255;
        dpk[r][c ^ ((r & 7) << 2)] = ld_na(src + i);
      }
      __syncthreads();
      int m = tid >> 4, sub = tid & 15, f = sub & 3, kq = sub >> 2;
      int swm = (m & 7) << 2;
      const float* owp = outW + f*H_ + kq*64;
      float s = 0.f;
#pragma unroll
      for (int i8 = 0; i8 < 8; ++i8){
        int base = kq*64 + i8*8;
        u32x4 pa = *(const u32x4*)&dpk[m][(base) ^ swm];
        u32x4 pb = *(const u32x4*)&dpk[m][(base+4) ^ swm];
        const float4 w0 = *(const float4*)(owp + i8*8);
        const float4 w1 = *(const float4*)(owp + i8*8 + 4);
        s += up_f(pa[0])*w0.x + up_f(pa[1])*w0.y + up_f(pa[2])*w0.z + up_f(pa[3])*w0.w;
        s += up_f(pb[0])*w1.x + up_f(pb[1])*w1.y + up_f(pb[2])*w1.z + up_f(pb[3])*w1.w;
      }
      s += __shfl_xor(s, 4);
      s += __shfl_xor(s, 8);
      if (kq == 0){
        float ov = s + outB[f];
        outlds[m][f] = ov;
        if (hc == 0) dout[(((size_t)(b0+m)*T_ + t)*3 + j)*F_ + f] = ov;
      }
    }
    __syncthreads();
    if (t < T_-1){
      for (int idx = tid; idx < 16*E_; idx += 256){
        int m = idx >> 7, ec = idx & 127;
        float s = dembB[ec];
#pragma unroll
        for (int f = 0; f < 4; ++f) s += outlds[m][f]*dembW[ec*4 + f];
        float e = fmaxf(s, 0.f);
        __hip_bfloat16 eh = __float2bfloat16(e);
        eldsH[m][ec] = eh;
        eldsL[m][ec] = __float2bfloat16(e - b2f(eh));
      }
      __syncthreads();
    }
  }
}

extern "C" void kernel_launch(void* const* d_in, const int* in_sizes, int n_in,
                              void* d_out, int out_size, void* d_ws, size_t ws_size,
                              hipStream_t stream)
{
  const float* x         = (const float*)d_in[0];
  const float* enc_lin_W = (const float*)d_in[2];
  const float* enc_lin_b = (const float*)d_in[3];
  const float* enc_Wih0  = (const float*)d_in[4];
  const float* enc_Wihs  = (const float*)d_in[5];
  const float* enc_Whh   = (const float*)d_in[6];
  const float* enc_bih   = (const float*)d_in[7];
  const float* enc_bhh   = (const float*)d_in[8];
  const float* dec_emb_W = (const float*)d_in[9];
  const float* dec_emb_b = (const float*)d_in[10];
  const float* attn_W    = (const float*)d_in[11];
  const float* dec_Wih0  = (const float*)d_in[13];
  const float* dec_Wihs  = (const float*)d_in[14];
  const float* dec_Whh   = (const float*)d_in[15];
  const float* dec_bih   = (const float*)d_in[16];
  const float* dec_bhh   = (const float*)d_in[17];
  const float* out_W     = (const float*)d_in[18];
  const float* out_b     = (const float*)d_in[19];
  const int*   p_to      = (const int*)d_in[20];
  float* dout = (float*)d_out;
  (void)in_sizes; (void)n_in; (void)out_size; (void)ws_size;

  char* ws = (char*)d_ws;
  size_t off = 0;
  auto take = [&](size_t nbytes) -> void* {
    void* p = ws + off; off += (nbytes + 255) & ~(size_t)255; return p; };
  unsigned int*   hpk     = (unsigned int*)take((size_t)4*G_*T_*B_*H_*4);     // packed h (enc)
  __hip_bfloat16* emb     = (__hip_bfloat16*)take((size_t)2*G_*T_*B_*E_*2);   // H+L
  float*          cbuf    = (float*)take((size_t)4*G_*B_*H_*4);
  __hip_bfloat16* wblob   = (__hip_bfloat16*)take((size_t)2*WBLOB_N*2);       // H+L
  __hip_bfloat16* attn_bf = (__hip_bfloat16*)take((size_t)2*64*256*2);        // H+L
  float*          Gc      = (float*)take((size_t)4*64*1024*4);
  unsigned int*   hpk2    = (unsigned int*)take((size_t)2*192*256*4);         // packed h (dec)
  unsigned int*   flags   = (unsigned int*)take(1024);
  unsigned int*   fenc    = flags;          // 176 slots
  unsigned int*   fdec    = flags + 256;    // 48 slots

  hipMemsetAsync(flags, 0, 1024, stream);
  k_conv<<<2048, 256, 0, stream>>>(enc_Wih0, enc_Wihs, enc_Whh, dec_Wih0, dec_Wihs, dec_Whh, wblob);
  k_emb<<<2048, 256, 0, stream>>>(x, enc_lin_W, enc_lin_b, emb);
  k_enc_p<<<176, 256, 0, stream>>>(hpk, emb, cbuf, wblob, enc_bih, enc_bhh, fenc, p_to);
  k_attn<<<64, 256, 0, stream>>>(hpk, attn_W, attn_bf);
  k_gc<<<16, 256, 0, stream>>>(hpk, attn_bf, wblob, dec_bih, dec_bhh, p_to, Gc);
  k_dec<<<48, 256, 0, stream>>>(x, cbuf, Gc, wblob, dec_emb_W, dec_emb_b, out_W, out_b,
                                hpk2, dout, fdec, p_to);
}

// Round 7
// 5071.397 us; speedup vs baseline: 1.8576x; 1.7383x over previous
//
#include <hip/hip_runtime.h>
#include <hip/hip_bf16.h>
#include <stdint.h>

#define B_ 64
#define T_ 64
#define G_ 11
#define F_ 4
#define E_ 128
#define H_ 256
#define NG 1024
#define GT_ 704

// weight blob region offsets (elements); lo-copy at +DW
#define OFF_WCAT0   0
#define OFF_WCAT123 393216
#define OFF_GCW0    1966080
#define OFF_GCW123  2490368
#define OFF_DWE     3276800
#define OFF_DWS     3407872
#define WBLOB_N     4194304
#define DW  ((size_t)WBLOB_N)
#define DE  ((size_t)5767168)     // emb lo-offset
#define DAT ((size_t)16384)       // attn lo-offset

typedef __attribute__((ext_vector_type(8))) short bf16x8;
typedef __attribute__((ext_vector_type(4))) float f32x4;
typedef __attribute__((ext_vector_type(4))) unsigned int u32x4;

__device__ __forceinline__ f32x4 mfma16(bf16x8 a, bf16x8 b, f32x4 c){
  return __builtin_amdgcn_mfma_f32_16x16x32_bf16(a, b, c, 0, 0, 0);
}
__device__ __forceinline__ float sigm(float x){ return 1.f/(1.f+__expf(-x)); }
__device__ __forceinline__ float tanh_(float x){ float e=__expf(2.f*x); return 1.f - 2.f/(e+1.f); }
__device__ __forceinline__ float b2f(__hip_bfloat16 v){ return __bfloat162float(v); }
__device__ __forceinline__ float s2f(short u){
  union { unsigned int u32; float f; } cv;
  cv.u32 = ((unsigned int)(unsigned short)u) << 16;
  return cv.f;
}
__device__ __forceinline__ void splitw(float v, __hip_bfloat16* ph, __hip_bfloat16* pl){
  __hip_bfloat16 h = __float2bfloat16(v);
  *ph = h; *pl = __float2bfloat16(v - __bfloat162float(h));
}
__device__ __forceinline__ unsigned int f2b(float f){
  unsigned int u = __float_as_uint(f);
  return (u + 0x7fffu + ((u>>16)&1u)) >> 16;
}
__device__ __forceinline__ unsigned int packsplit(float v){
  unsigned int hb = f2b(v);
  float hf = __uint_as_float(hb<<16);
  unsigned int lb = f2b(v - hf);
  return (hb<<16) | lb;
}
__device__ __forceinline__ float up_f(unsigned int u){
  return __uint_as_float(u & 0xffff0000u) + __uint_as_float(u << 16);
}
// flags: relaxed device-scope atomics (dword, no cache invalidation)
__device__ __forceinline__ unsigned int ld_na(const unsigned int* p){
  return __hip_atomic_load(p, __ATOMIC_RELAXED, __HIP_MEMORY_SCOPE_AGENT);
}
__device__ __forceinline__ void st_na(unsigned int* p, unsigned int v){
  __hip_atomic_store(p, v, __ATOMIC_RELAXED, __HIP_MEMORY_SCOPE_AGENT);
}
// bulk coherent traffic: device-scope (sc1) wide loads / stores, pipelined
__device__ __forceinline__ void ldg4_sc1(u32x4* d, const unsigned int* p){
  asm volatile("global_load_dwordx4 %0, %1, off sc1" : "=v"(*d) : "v"(p) : "memory");
}
__device__ __forceinline__ void stg1_sc1(unsigned int* p, unsigned int v){
  asm volatile("global_store_dword %0, %1, off sc1" :: "v"(p), "v"(v) : "memory");
}
__device__ __forceinline__ void wait_vm0(){
  asm volatile("s_waitcnt vmcnt(0)" ::: "memory");
  __builtin_amdgcn_sched_barrier(0);
}

// ---------------- weight conversion fp32 -> split bf16 (hi/lo blobs) -----------
__global__ void k_conv(const float* Wih0, const float* Wihs, const float* Whh,
                       const float* dWih0, const float* dWihs, const float* dWhh,
                       __hip_bfloat16* out)
{
  for (int i = blockIdx.x*blockDim.x + threadIdx.x; i < WBLOB_N; i += gridDim.x*blockDim.x){
    int j = i; float v;
    if (j < 393216) {                       // Wcat0 [1024][384]
      int n = j/384, k = j%384;
      v = (k<128) ? Wih0[n*128+k] : Whh[n*256 + (k-128)];
    } else if ((j -= 393216) < 1572864) {   // Wcat123 3x[1024][512]
      int l = j/524288; int r = j%524288; int n = r/512, k = r%512;
      v = (k<256) ? Wihs[(l*1024+n)*256+k] : Whh[((l+1)*1024+n)*256 + (k-256)];
    } else if ((j -= 1572864) < 524288) {   // GcW0 [1024][512]
      int n = j/512, k = j%512;
      v = (k<256) ? dWih0[n*384+k] : dWhh[n*256 + (k-256)];
    } else if ((j -= 524288) < 786432) {    // GcW123 3x[1024][256]
      int l = j/262144; int r = j%262144; int n = r/256, k = r%256;
      v = dWhh[((l+1)*1024+n)*256+k];
    } else if ((j -= 786432) < 131072) {    // dWe [1024][128]
      int n = j/128, k = j%128;
      v = dWih0[n*384 + 256 + k];
    } else { j -= 131072; v = dWihs[j]; }   // dWs 3x[1024][256]
    splitw(v, out + i, out + i + DW);
  }
}

// ---------------- emb = relu(xg @ enc_lin_W^T + b), split bf16 ------------------
__global__ void k_emb(const float* x, const float* W, const float* bb, __hip_bfloat16* emb)
{
  const int N = G_*T_*B_*E_;
  for (int i = blockIdx.x*blockDim.x + threadIdx.x; i < N; i += gridDim.x*blockDim.x){
    int e = i & 127; int row = i >> 7;
    int b = row & 63; int t = (row >> 6) & 63; int g = row >> 12;
    const float* xp = x + ((size_t)(b*T_ + t)*G_ + g)*F_;
    float s = bb[e];
#pragma unroll
    for (int f = 0; f < 4; ++f) s += xp[f]*W[e*4+f];
    splitw(fmaxf(s, 0.f), emb + i, emb + i + DE);
  }
}

// ---------------- persistent encoder: bid=g*16+l*4+hc, loops t=0..63 ------------
// wave wv owns cols hc*64+wv*16+lm for all 4 gates, all 64 rows (no dup weights)
__global__ __launch_bounds__(256) void k_enc_p(
  unsigned int* hpk, const __hip_bfloat16* emb, float* cbuf,
  const __hip_bfloat16* wb, const float* bih, const float* bhh,
  unsigned int* fe, const int* p_to)
{
  const int bid = blockIdx.x;
  const int g = bid >> 4, l = (bid >> 2) & 3, hc = bid & 3;
  const int grp = l*G_ + g, pgrp = grp - G_;
  const int to = *p_to;
  const int tid = threadIdx.x, wv = tid >> 6, lane = tid & 63;
  const int lm = lane & 15, lk = (lane >> 4)*8;
  const int colc = hc*64 + wv*16 + lm;      // h-col this lane owns

  const __hip_bfloat16* W; int wstride, KX;
  if (l == 0){ W = wb + OFF_WCAT0; wstride = 384; KX = E_; }
  else { W = wb + OFF_WCAT123 + (size_t)(l-1)*1024*512; wstride = 512; KX = H_; }

  const __hip_bfloat16* wp[4];
#pragma unroll
  for (int q = 0; q < 4; ++q)
    wp[q] = W + (size_t)(q*256 + colc)*wstride + lk;

  float bsum[4];
#pragma unroll
  for (int q = 0; q < 4; ++q)
    bsum[q] = bih[l*NG + q*256 + colc] + bhh[l*NG + q*256 + colc];

  float creg[4][4];
#pragma unroll
  for (int mt = 0; mt < 4; ++mt)
#pragma unroll
    for (int r = 0; r < 4; ++r) creg[mt][r] = 0.f;

  unsigned int* hpl = hpk + (size_t)grp*T_*B_*H_;
  const unsigned int* psrc = (l > 0) ? (hpk + (size_t)pgrp*T_*B_*H_) : nullptr;

  __shared__ char ldsw[65536];   // hi plane [64][256]bf16 @0, lo plane @32768

  // stage one 64x256 packed tile -> swizzled hi/lo LDS planes (2 bursts of 8x16B)
  auto STAGE = [&](const unsigned int* src){
#pragma unroll
    for (int half = 0; half < 2; ++half){
      u32x4 tmp[8];
#pragma unroll
      for (int i = 0; i < 8; ++i)
        ldg4_sc1(&tmp[i], src + (size_t)(tid + 256*(half*8 + i))*4);
      wait_vm0();
#pragma unroll
      for (int i = 0; i < 8; ++i){
        int chunk = tid + 256*(half*8 + i);
        int r = chunk >> 6, cb8 = (chunk & 63) << 3;
        int off = (r << 9) + (cb8 ^ ((r & 7) << 4));
        uint2 hv, lv;
        hv.x = (tmp[i][0] >> 16) | (tmp[i][1] & 0xffff0000u);
        hv.y = (tmp[i][2] >> 16) | (tmp[i][3] & 0xffff0000u);
        lv.x = (tmp[i][0] & 0xffffu) | (tmp[i][1] << 16);
        lv.y = (tmp[i][2] & 0xffffu) | (tmp[i][3] << 16);
        *reinterpret_cast<uint2*>(ldsw + off) = hv;
        *reinterpret_cast<uint2*>(ldsw + 32768 + off) = lv;
      }
    }
  };

  for (int t = 0; t < T_; ++t){
    if (t > 0 && tid < 4){
      while (ld_na(&fe[grp*4 + tid]) < (unsigned int)t) __builtin_amdgcn_s_sleep(1);
    }
    if (l > 0 && tid >= 4 && tid < 8){
      while (ld_na(&fe[pgrp*4 + (tid-4)]) < (unsigned int)(t+1)) __builtin_amdgcn_s_sleep(1);
    }
    __syncthreads();

    f32x4 acc[4][4];
#pragma unroll
    for (int mt = 0; mt < 4; ++mt)
#pragma unroll
      for (int q = 0; q < 4; ++q) acc[mt][q] = (f32x4)0.f;

    // ---- phase A: x-input GEMM ----
    if (l == 0){
      const __hip_bfloat16* xin = emb + ((size_t)g*T_ + t)*B_*E_;
      for (int ka = 0; ka < E_; ka += 32){
        bf16x8 ah[4], al[4];
#pragma unroll
        for (int mt = 0; mt < 4; ++mt){
          const __hip_bfloat16* ap = xin + (size_t)(mt*16 + lm)*E_ + lk + ka;
          ah[mt] = *(const bf16x8*)ap;
          al[mt] = *(const bf16x8*)(ap + DE);
        }
#pragma unroll
        for (int q = 0; q < 4; ++q){
          bf16x8 bh = *(const bf16x8*)(wp[q] + ka);
          bf16x8 bl = *(const bf16x8*)(wp[q] + ka + DW);
#pragma unroll
          for (int mt = 0; mt < 4; ++mt){
            acc[mt][q] = mfma16(ah[mt], bh, acc[mt][q]);
            acc[mt][q] = mfma16(ah[mt], bl, acc[mt][q]);
            acc[mt][q] = mfma16(al[mt], bh, acc[mt][q]);
          }
        }
      }
    } else {
      STAGE(psrc + (size_t)t*B_*H_);
      __syncthreads();
      for (int ks = 0; ks < 8; ++ks){
        int kb = ks*64 + (lane >> 4)*16;
        bf16x8 ah[4], al[4];
#pragma unroll
        for (int mt = 0; mt < 4; ++mt){
          int R = mt*16 + lm;
          int off = (R << 9) + (kb ^ ((lm & 7) << 4));
          ah[mt] = *reinterpret_cast<const bf16x8*>(ldsw + off);
          al[mt] = *reinterpret_cast<const bf16x8*>(ldsw + 32768 + off);
        }
#pragma unroll
        for (int q = 0; q < 4; ++q){
          bf16x8 bh = *(const bf16x8*)(wp[q] + ks*32);
          bf16x8 bl = *(const bf16x8*)(wp[q] + ks*32 + DW);
#pragma unroll
          for (int mt = 0; mt < 4; ++mt){
            acc[mt][q] = mfma16(ah[mt], bh, acc[mt][q]);
            acc[mt][q] = mfma16(ah[mt], bl, acc[mt][q]);
            acc[mt][q] = mfma16(al[mt], bh, acc[mt][q]);
          }
        }
      }
      __syncthreads();  // all reads done before LDS reuse
    }
    // ---- phase B: recurrent GEMM ----
    if (t > 0){
      STAGE(hpl + (size_t)(t-1)*B_*H_);
      __syncthreads();
      for (int ks = 0; ks < 8; ++ks){
        int kb = ks*64 + (lane >> 4)*16;
        bf16x8 ah[4], al[4];
#pragma unroll
        for (int mt = 0; mt < 4; ++mt){
          int R = mt*16 + lm;
          int off = (R << 9) + (kb ^ ((lm & 7) << 4));
          ah[mt] = *reinterpret_cast<const bf16x8*>(ldsw + off);
          al[mt] = *reinterpret_cast<const bf16x8*>(ldsw + 32768 + off);
        }
#pragma unroll
        for (int q = 0; q < 4; ++q){
          bf16x8 bh = *(const bf16x8*)(wp[q] + KX + ks*32);
          bf16x8 bl = *(const bf16x8*)(wp[q] + KX + ks*32 + DW);
#pragma unroll
          for (int mt = 0; mt < 4; ++mt){
            acc[mt][q] = mfma16(ah[mt], bh, acc[mt][q]);
            acc[mt][q] = mfma16(ah[mt], bl, acc[mt][q]);
            acc[mt][q] = mfma16(al[mt], bh, acc[mt][q]);
          }
        }
      }
    }

    // ---- register epilogue: gates -> h,c; pack + sc1 dword stores ----
    unsigned int* hdst = hpl + (size_t)t*B_*H_;
#pragma unroll
    for (int mt = 0; mt < 4; ++mt)
#pragma unroll
      for (int r = 0; r < 4; ++r){
        float gi = acc[mt][0][r] + bsum[0];
        float gf = acc[mt][1][r] + bsum[1];
        float gg = acc[mt][2][r] + bsum[2];
        float go = acc[mt][3][r] + bsum[3];
        float c2 = sigm(gf)*creg[mt][r] + sigm(gi)*tanh_(gg);
        float h2 = sigm(go)*tanh_(c2);
        creg[mt][r] = c2;
        int row = mt*16 + (lane >> 4)*4 + r;
        stg1_sc1(hdst + (size_t)row*H_ + colc, packsplit(h2));
        if (t == T_-1 && g == to)
          cbuf[((size_t)l*G_ + g)*B_*H_ + (size_t)row*H_ + colc] = c2;
      }
    wait_vm0();        // ensure sc1 stores drained even though asm-issued
    __syncthreads();
    if (tid == 0) st_na(&fe[grp*4 + hc], (unsigned int)(t+1));
  }
}

// ---------------- attention (hq.wa_h and attn_b cancel in softmax) --------------
__global__ __launch_bounds__(256) void k_attn(
  const unsigned int* hpk, const float* attnW, __hip_bfloat16* attn_bf)
{
  const int b = blockIdx.x; const int tid = threadIdx.x;
  const unsigned int* enc = hpk + (size_t)3*G_*T_*B_*H_;   // [gt][b][h] packed
  const float* wa_e = attnW + 256;
  __shared__ float sw_[GT_];
  __shared__ float red[256];

  for (int it = 0; it < (GT_*4)/256; ++it){
    int idx = tid + it*256;
    int gt = idx >> 2, p = idx & 3;
    const unsigned int* ep = enc + ((size_t)gt*B_ + b)*H_ + p*64;
    float s = 0.f;
    for (int h = 0; h < 64; ++h) s += up_f(ep[h]) * wa_e[p*64 + h];
    s += __shfl_xor(s, 1);
    s += __shfl_xor(s, 2);
    if (p == 0) sw_[gt] = s;
  }
  __syncthreads();
  float lmax = -1e30f;
  for (int idx = tid; idx < GT_; idx += 256) lmax = fmaxf(lmax, sw_[idx]);
  red[tid] = lmax; __syncthreads();
  for (int s2 = 128; s2 > 0; s2 >>= 1){ if (tid < s2) red[tid] = fmaxf(red[tid], red[tid+s2]); __syncthreads(); }
  float M = red[0]; __syncthreads();
  float lsum = 0.f;
  for (int idx = tid; idx < GT_; idx += 256) lsum += __expf(sw_[idx] - M);
  red[tid] = lsum; __syncthreads();
  for (int s2 = 128; s2 > 0; s2 >>= 1){ if (tid < s2) red[tid] += red[tid+s2]; __syncthreads(); }
  float Z = red[0]; __syncthreads();
  for (int idx = tid; idx < GT_; idx += 256) sw_[idx] = __expf(sw_[idx] - M) / Z;
  __syncthreads();
  float acc = 0.f;
  const unsigned int* ep = enc + (size_t)b*H_ + tid;
  for (int gt = 0; gt < GT_; ++gt) acc += sw_[gt] * up_f(ep[(size_t)gt*B_*H_]);
  splitw(acc, attn_bf + b*H_ + tid, attn_bf + DAT + b*H_ + tid);
}

#define UNPK8(pa, pb, h8, l8) \
  { _Pragma("unroll") for (int q2_ = 0; q2_ < 4; ++q2_){ \
      h8[q2_]   = (short)(pa[q2_] >> 16); l8[q2_]   = (short)(pa[q2_] & 0xffffu); \
      h8[4+q2_] = (short)(pb[q2_] >> 16); l8[4+q2_] = (short)(pb[q2_] & 0xffffu); } }

// ---------------- Gc[l][b][1024] = const gate part of decoder cells -------------
__global__ __launch_bounds__(256) void k_gc(
  const unsigned int* hpk, const __hip_bfloat16* attn_bf,
  const __hip_bfloat16* wb, const float* dbih, const float* dbhh,
  const int* p_to, float* Gc)
{
  const int to = *p_to;
  const int l = blockIdx.x >> 2, cb4 = blockIdx.x & 3;
  const int tid = threadIdx.x, wv = tid >> 6, lane = tid & 63;
  const int rowblk = (wv & 1)*32, colblk = (wv >> 1)*128;
  const int lm = lane & 15, lk = (lane >> 4)*8;
  const unsigned int* dech = hpk + ((size_t)(l*G_ + to)*T_ + 63)*B_*H_;
  const __hip_bfloat16* W; int wstride;
  if (l == 0){ W = wb + OFF_GCW0; wstride = 512; }
  else { W = wb + OFF_GCW123 + (size_t)(l-1)*1024*256; wstride = 256; }
  const __hip_bfloat16* wp[8];
#pragma unroll
  for (int cb = 0; cb < 8; ++cb){
    int n = cb4*256 + colblk + cb*16 + lm;
    wp[cb] = W + (size_t)n*wstride + lk;
  }
  f32x4 acc[2][8];
#pragma unroll
  for (int i = 0; i < 2; ++i)
#pragma unroll
    for (int cb = 0; cb < 8; ++cb) acc[i][cb] = (f32x4)0.f;

  if (l == 0){
    const __hip_bfloat16* a0p = attn_bf + (size_t)(rowblk + lm)*H_ + lk;
    const __hip_bfloat16* a1p = attn_bf + (size_t)(rowblk + 16 + lm)*H_ + lk;
    for (int ka = 0; ka < 256; ka += 32){
      bf16x8 a0h = *(const bf16x8*)(a0p + ka);
      bf16x8 a0l = *(const bf16x8*)(a0p + ka + DAT);
      bf16x8 a1h = *(const bf16x8*)(a1p + ka);
      bf16x8 a1l = *(const bf16x8*)(a1p + ka + DAT);
#pragma unroll
      for (int cb = 0; cb < 8; ++cb){
        bf16x8 bh = *(const bf16x8*)(wp[cb] + ka);
        bf16x8 bl = *(const bf16x8*)(wp[cb] + ka + DW);
        acc[0][cb] = mfma16(a0h, bh, acc[0][cb]);
        acc[0][cb] = mfma16(a0h, bl, acc[0][cb]);
        acc[0][cb] = mfma16(a0l, bh, acc[0][cb]);
        acc[1][cb] = mfma16(a1h, bh, acc[1][cb]);
        acc[1][cb] = mfma16(a1h, bl, acc[1][cb]);
        acc[1][cb] = mfma16(a1l, bh, acc[1][cb]);
      }
    }
  }
  const int koff = (l == 0) ? 256 : 0;
  for (int ka = 0; ka < 256; ka += 32){
    bf16x8 a0h,a0l,a1h,a1l;
    { const unsigned int* p0 = dech + (size_t)(rowblk + lm)*H_ + ka + lk;
      u32x4 pa = *(const u32x4*)p0; u32x4 pb = *(const u32x4*)(p0 + 4);
      UNPK8(pa, pb, a0h, a0l); }
    { const unsigned int* p1 = dech + (size_t)(rowblk + 16 + lm)*H_ + ka + lk;
      u32x4 pa = *(const u32x4*)p1; u32x4 pb = *(const u32x4*)(p1 + 4);
      UNPK8(pa, pb, a1h, a1l); }
#pragma unroll
    for (int cb = 0; cb < 8; ++cb){
      bf16x8 bh = *(const bf16x8*)(wp[cb] + koff + ka);
      bf16x8 bl = *(const bf16x8*)(wp[cb] + koff + ka + DW);
      acc[0][cb] = mfma16(a0h, bh, acc[0][cb]);
      acc[0][cb] = mfma16(a0h, bl, acc[0][cb]);
      acc[0][cb] = mfma16(a0l, bh, acc[0][cb]);
      acc[1][cb] = mfma16(a1h, bh, acc[1][cb]);
      acc[1][cb] = mfma16(a1h, bl, acc[1][cb]);
      acc[1][cb] = mfma16(a1l, bh, acc[1][cb]);
    }
  }
#pragma unroll
  for (int i = 0; i < 2; ++i)
#pragma unroll
    for (int cb = 0; cb < 8; ++cb){
      int row = rowblk + i*16 + (lane >> 4)*4;
      int n = cb4*256 + colblk + cb*16 + lm;
#pragma unroll
      for (int r = 0; r < 4; ++r)
        Gc[((size_t)l*64 + (row + r))*NG + n] = acc[i][cb][r] + dbih[l*NG + n] + dbhh[l*NG + n];
    }
}

// ---------------- persistent decoder: sc1 bursts + planes, register epilogue ----
__global__ __launch_bounds__(256) void k_dec(
  const float* x, const float* cbuf, const float* Gc, const __hip_bfloat16* wb,
  const float* dembW, const float* dembB,
  const float* outW, const float* outB,
  unsigned int* hpk2, float* dout, unsigned int* flags, const int* p_to)
{
  const int to = *p_to;
  const int rt = blockIdx.x >> 2, hc = blockIdx.x & 3;
  const int j = rt >> 2, b0 = (rt & 3)*16;
  const int R0 = rt*16;
  const int tid = threadIdx.x, wv = tid >> 6, lane = tid & 63;
  const int lm = lane & 15, lk = (lane >> 4)*8;
  const int myc = hc*64 + wv*16 + lm;
  const int m_  = (lane >> 4)*4;
  unsigned int* slots = flags + rt*4;

  float gc[4][4][4];
  float cp[4][4];
#pragma unroll
  for (int l = 0; l < 4; ++l)
#pragma unroll
    for (int r = 0; r < 4; ++r){
      cp[l][r] = cbuf[((size_t)l*G_ + to)*B_*H_ + (size_t)(b0 + m_ + r)*H_ + myc];
#pragma unroll
      for (int q = 0; q < 4; ++q)
        gc[l][q][r] = Gc[((size_t)l*64 + (b0 + m_ + r))*NG + q*256 + myc];
    }

  __shared__ char dpl[16384];                // hi plane [16][256]bf16 @0, lo @8192
  __shared__ __hip_bfloat16 eldsH[16][136];
  __shared__ __hip_bfloat16 eldsL[16][136];
  __shared__ float outlds[16][4];
  unsigned int done = 0;

  auto STAGE16 = [&](const unsigned int* src){
    u32x4 tmp[4];
#pragma unroll
    for (int i = 0; i < 4; ++i)
      ldg4_sc1(&tmp[i], src + (size_t)(tid + 256*i)*4);
    wait_vm0();
#pragma unroll
    for (int i = 0; i < 4; ++i){
      int chunk = tid + 256*i;
      int r = chunk >> 6, cb8 = (chunk & 63) << 3;
      int off = (r << 9) + (cb8 ^ ((r & 7) << 4));
      uint2 hv, lv;
      hv.x = (tmp[i][0] >> 16) | (tmp[i][1] & 0xffff0000u);
      hv.y = (tmp[i][2] >> 16) | (tmp[i][3] & 0xffff0000u);
      lv.x = (tmp[i][0] & 0xffffu) | (tmp[i][1] << 16);
      lv.y = (tmp[i][2] & 0xffffu) | (tmp[i][3] << 16);
      *reinterpret_cast<uint2*>(dpl + off) = hv;
      *reinterpret_cast<uint2*>(dpl + 8192 + off) = lv;
    }
  };

  if (tid < 64){
    int m = tid >> 2, f = tid & 3;
    outlds[m][f] = x[((size_t)((b0+m)*T_ + 63)*G_ + (to + j))*F_ + f];
  }
  __syncthreads();
  for (int idx = tid; idx < 16*E_; idx += 256){
    int m = idx >> 7, ec = idx & 127;
    float s = dembB[ec];
#pragma unroll
    for (int f = 0; f < 4; ++f) s += outlds[m][f]*dembW[ec*4 + f];
    float e = fmaxf(s, 0.f);
    __hip_bfloat16 eh = __float2bfloat16(e);
    eldsH[m][ec] = eh;
    eldsL[m][ec] = __float2bfloat16(e - b2f(eh));
  }
  __syncthreads();

  for (int t = 0; t < T_; ++t){
    for (int l = 0; l < 4; ++l){
      if (l > 0){
        STAGE16(hpk2 + (size_t)((l-1)&1)*192*H_ + (size_t)R0*H_);
        __syncthreads();
      }
      const __hip_bfloat16* W; int wstride, ksteps;
      if (l == 0){ W = wb + OFF_DWE; wstride = E_; ksteps = 4; }
      else { W = wb + OFF_DWS + (size_t)(l-1)*1024*256; wstride = H_; ksteps = 8; }
      const __hip_bfloat16* wpd[4];
#pragma unroll
      for (int q = 0; q < 4; ++q)
        wpd[q] = W + (size_t)(q*256 + myc)*wstride + lk;

      f32x4 acc[4];
#pragma unroll
      for (int q = 0; q < 4; ++q) acc[q] = (f32x4)0.f;

      for (int ks = 0; ks < ksteps; ++ks){
        bf16x8 ah, al;
        if (l == 0){
          ah = *(const bf16x8*)(&eldsH[lm][ks*32 + lk]);
          al = *(const bf16x8*)(&eldsL[lm][ks*32 + lk]);
        } else {
          int kb = ks*64 + (lane >> 4)*16;
          int off = (lm << 9) + (kb ^ ((lm & 7) << 4));
          ah = *reinterpret_cast<const bf16x8*>(dpl + off);
          al = *reinterpret_cast<const bf16x8*>(dpl + 8192 + off);
        }
#pragma unroll
        for (int q = 0; q < 4; ++q){
          bf16x8 bh = *(const bf16x8*)(wpd[q] + ks*32);
          bf16x8 bl = *(const bf16x8*)(wpd[q] + ks*32 + DW);
          acc[q] = mfma16(ah, bh, acc[q]);
          acc[q] = mfma16(ah, bl, acc[q]);
          acc[q] = mfma16(al, bh, acc[q]);
        }
      }
      unsigned int* hdst = hpk2 + (size_t)(l&1)*192*H_;
#pragma unroll
      for (int r = 0; r < 4; ++r){
        float gi = acc[0][r] + gc[l][0][r];
        float gf = acc[1][r] + gc[l][1][r];
        float gg = acc[2][r] + gc[l][2][r];
        float go = acc[3][r] + gc[l][3][r];
        float c2 = sigm(gf)*cp[l][r] + sigm(gi)*tanh_(gg);
        float h2v = sigm(go)*tanh_(c2);
        stg1_sc1(hdst + (size_t)(R0 + m_ + r)*H_ + myc, packsplit(h2v));
      }
      wait_vm0();
      __syncthreads();
      done++;
      if (tid == 0) st_na(&slots[hc], done);
      if (tid < 4){
        while (ld_na(&slots[tid]) < done) __builtin_amdgcn_s_sleep(1);
      }
      __syncthreads();
    }

    // out-GEMM from restaged h3 planes + dout + next elds
    {
      STAGE16(hpk2 + (size_t)1*192*H_ + (size_t)R0*H_);
      __syncthreads();
      int m = tid >> 4, sub = tid & 15, f = sub & 3, kq = sub >> 2;
      const float* owp = outW + f*H_ + kq*64;
      float s = 0.f;
#pragma unroll
      for (int i8 = 0; i8 < 8; ++i8){
        int off = (m << 9) + (((kq*128) + i8*16) ^ ((m & 7) << 4));
        bf16x8 hh = *reinterpret_cast<const bf16x8*>(dpl + off);
        bf16x8 hl = *reinterpret_cast<const bf16x8*>(dpl + 8192 + off);
        const float4 w0 = *(const float4*)(owp + i8*8);
        const float4 w1 = *(const float4*)(owp + i8*8 + 4);
        s += (s2f(hh[0])+s2f(hl[0]))*w0.x; s += (s2f(hh[1])+s2f(hl[1]))*w0.y;
        s += (s2f(hh[2])+s2f(hl[2]))*w0.z; s += (s2f(hh[3])+s2f(hl[3]))*w0.w;
        s += (s2f(hh[4])+s2f(hl[4]))*w1.x; s += (s2f(hh[5])+s2f(hl[5]))*w1.y;
        s += (s2f(hh[6])+s2f(hl[6]))*w1.z; s += (s2f(hh[7])+s2f(hl[7]))*w1.w;
      }
      s += __shfl_xor(s, 4);
      s += __shfl_xor(s, 8);
      if (kq == 0){
        float ov = s + outB[f];
        outlds[m][f] = ov;
        if (hc == 0) dout[(((size_t)(b0+m)*T_ + t)*3 + j)*F_ + f] = ov;
      }
    }
    __syncthreads();
    if (t < T_-1){
      for (int idx = tid; idx < 16*E_; idx += 256){
        int m = idx >> 7, ec = idx & 127;
        float s = dembB[ec];
#pragma unroll
        for (int f = 0; f < 4; ++f) s += outlds[m][f]*dembW[ec*4 + f];
        float e = fmaxf(s, 0.f);
        __hip_bfloat16 eh = __float2bfloat16(e);
        eldsH[m][ec] = eh;
        eldsL[m][ec] = __float2bfloat16(e - b2f(eh));
      }
      __syncthreads();
    }
  }
}

extern "C" void kernel_launch(void* const* d_in, const int* in_sizes, int n_in,
                              void* d_out, int out_size, void* d_ws, size_t ws_size,
                              hipStream_t stream)
{
  const float* x         = (const float*)d_in[0];
  const float* enc_lin_W = (const float*)d_in[2];
  const float* enc_lin_b = (const float*)d_in[3];
  const float* enc_Wih0  = (const float*)d_in[4];
  const float* enc_Wihs  = (const float*)d_in[5];
  const float* enc_Whh   = (const float*)d_in[6];
  const float* enc_bih   = (const float*)d_in[7];
  const float* enc_bhh   = (const float*)d_in[8];
  const float* dec_emb_W = (const float*)d_in[9];
  const float* dec_emb_b = (const float*)d_in[10];
  const float* attn_W    = (const float*)d_in[11];
  const float* dec_Wih0  = (const float*)d_in[13];
  const float* dec_Wihs  = (const float*)d_in[14];
  const float* dec_Whh   = (const float*)d_in[15];
  const float* dec_bih   = (const float*)d_in[16];
  const float* dec_bhh   = (const float*)d_in[17];
  const float* out_W     = (const float*)d_in[18];
  const float* out_b     = (const float*)d_in[19];
  const int*   p_to      = (const int*)d_in[20];
  float* dout = (float*)d_out;
  (void)in_sizes; (void)n_in; (void)out_size; (void)ws_size;

  char* ws = (char*)d_ws;
  size_t off = 0;
  auto take = [&](size_t nbytes) -> void* {
    void* p = ws + off; off += (nbytes + 255) & ~(size_t)255; return p; };
  unsigned int*   hpk     = (unsigned int*)take((size_t)4*G_*T_*B_*H_*4);     // packed h (enc)
  __hip_bfloat16* emb     = (__hip_bfloat16*)take((size_t)2*G_*T_*B_*E_*2);   // H+L
  float*          cbuf    = (float*)take((size_t)4*G_*B_*H_*4);
  __hip_bfloat16* wblob   = (__hip_bfloat16*)take((size_t)2*WBLOB_N*2);       // H+L
  __hip_bfloat16* attn_bf = (__hip_bfloat16*)take((size_t)2*64*256*2);        // H+L
  float*          Gc      = (float*)take((size_t)4*64*1024*4);
  unsigned int*   hpk2    = (unsigned int*)take((size_t)2*192*256*4);         // packed h (dec)
  unsigned int*   flags   = (unsigned int*)take(1024);
  unsigned int*   fenc    = flags;          // 176 slots
  unsigned int*   fdec    = flags + 256;    // 48 slots

  hipMemsetAsync(flags, 0, 1024, stream);
  k_conv<<<2048, 256, 0, stream>>>(enc_Wih0, enc_Wihs, enc_Whh, dec_Wih0, dec_Wihs, dec_Whh, wblob);
  k_emb<<<2048, 256, 0, stream>>>(x, enc_lin_W, enc_lin_b, emb);
  k_enc_p<<<176, 256, 0, stream>>>(hpk, emb, cbuf, wblob, enc_bih, enc_bhh, fenc, p_to);
  k_attn<<<64, 256, 0, stream>>>(hpk, attn_W, attn_bf);
  k_gc<<<16, 256, 0, stream>>>(hpk, attn_bf, wblob, dec_bih, dec_bhh, p_to, Gc);
  k_dec<<<48, 256, 0, stream>>>(x, cbuf, Gc, wblob, dec_emb_W, dec_emb_b, out_W, out_b,
                                hpk2, dout, fdec, p_to);
}